// Round 1
// baseline (695.765 us; speedup 1.0000x reference)
//
#include <hip/hip_runtime.h>
#include <math.h>

#define TNUM 8192
#define BNUM 8
#define DV 1024
#define DQ 768
#define KREP 6
#define NHEAD 8
#define HD 128
#define CANDN 18

// ---------------- helpers ----------------
__device__ __forceinline__ double wave_reduce_sum(double v) {
    for (int off = 32; off > 0; off >>= 1) v += __shfl_down(v, off);
    return v;
}
__device__ __forceinline__ float wave_reduce_sumf(float v) {
    for (int off = 32; off > 0; off >>= 1) v += __shfl_down(v, off);
    return v;
}

// monotone map: double -> uint64 preserving order
__device__ __forceinline__ unsigned long long enc_d(double d) {
    unsigned long long u = (unsigned long long)__double_as_longlong(d);
    return (u >> 63) ? ~u : (u | 0x8000000000000000ULL);
}
__device__ __forceinline__ double dec_d(unsigned long long e) {
    unsigned long long u = (e >> 63) ? (e ^ 0x8000000000000000ULL) : ~e;
    return __longlong_as_double((long long)u);
}

// ---------------- K1: h = x @ w1.T + b1 (both branches, f64) ----------------
__global__ void k_mlp1(const float* __restrict__ q,
                       const float* __restrict__ mu_w1, const float* __restrict__ mu_b1,
                       const float* __restrict__ sg_w1, const float* __restrict__ sg_b1,
                       double* __restrict__ h) {
    int o = blockIdx.x, b = blockIdx.y, br = blockIdx.z;
    const float* w  = br ? sg_w1 : mu_w1;
    const float* bb = br ? sg_b1 : mu_b1;
    const float* x  = q + (size_t)b * DQ;
    const float* wr = w + (size_t)o * DQ;
    double acc = 0.0;
    for (int j = threadIdx.x; j < DQ; j += 64)
        acc += (double)x[j] * (double)wr[j];
    acc = wave_reduce_sum(acc);
    if (threadIdx.x == 0)
        h[((size_t)br * BNUM + b) * DV + o] = acc + (double)bb[o];
}

// ---------------- K2: LayerNorm + ReLU in-place (f64) ----------------
__global__ void k_ln(double* __restrict__ h,
                     const float* __restrict__ mg, const float* __restrict__ mbt,
                     const float* __restrict__ sg, const float* __restrict__ sbt) {
    int b = blockIdx.x, br = blockIdx.y;
    const float* g  = br ? sg  : mg;
    const float* bt = br ? sbt : mbt;
    double* row = h + ((size_t)br * BNUM + b) * DV;
    __shared__ double sc[4];
    __shared__ double s_mean, s_rstd;
    int tid = threadIdx.x, wid = tid >> 6, lane = tid & 63;

    double s = 0.0;
    for (int j = tid; j < DV; j += 256) s += row[j];
    s = wave_reduce_sum(s);
    if (lane == 0) sc[wid] = s;
    __syncthreads();
    if (tid == 0) s_mean = (sc[0] + sc[1] + sc[2] + sc[3]) / (double)DV;
    __syncthreads();
    double mean = s_mean;

    double v = 0.0;
    for (int j = tid; j < DV; j += 256) { double c = row[j] - mean; v += c * c; }
    v = wave_reduce_sum(v);
    if (lane == 0) sc[wid] = v;
    __syncthreads();
    if (tid == 0) s_rstd = 1.0 / sqrt((sc[0] + sc[1] + sc[2] + sc[3]) / (double)DV + 1e-5);
    __syncthreads();
    double rstd = s_rstd;

    for (int j = tid; j < DV; j += 256) {
        double val = (row[j] - mean) * rstd * (double)g[j] + (double)bt[j];
        row[j] = val > 0.0 ? val : 0.0;
    }
}

// ---------------- K3: out = h2 @ w2.T + b2; mu / softplus-sigma (f64) ----------------
__global__ void k_mlp2(const double* __restrict__ h,
                       const float* __restrict__ mu_w2, const float* __restrict__ mu_b2,
                       const float* __restrict__ sg_w2, const float* __restrict__ sg_b2,
                       double* __restrict__ mu, double* __restrict__ rsig,
                       float* __restrict__ out_mu, float* __restrict__ out_sg) {
    int o = blockIdx.x, b = blockIdx.y, br = blockIdx.z;
    const float* w  = br ? sg_w2 : mu_w2;
    const float* bb = br ? sg_b2 : mu_b2;
    const double* row = h + ((size_t)br * BNUM + b) * DV;
    const float* wr = w + (size_t)o * DV;
    double acc = 0.0;
    for (int j = threadIdx.x; j < DV; j += 64)
        acc += row[j] * (double)wr[j];
    acc = wave_reduce_sum(acc);
    if (threadIdx.x == 0) {
        double v = acc + (double)bb[o];
        if (br == 0) {
            mu[(size_t)b * DV + o] = v;
            out_mu[b * DV + o] = (float)v;
        } else {
            double sp = fmax(v, 0.0) + log1p(exp(-fabs(v)));  // stable softplus
            double sig = sp + 1e-6;
            rsig[(size_t)b * DV + o] = 1.0 / sig;
            out_sg[b * DV + o] = (float)sig;
        }
    }
}

// ---------------- K4: Mahalanobis dist (the 256 MiB streaming kernel) ----------------
__global__ void k_dist(const float* __restrict__ feat,
                       const double* __restrict__ mu, const double* __restrict__ rsig,
                       double* __restrict__ distw, float* __restrict__ dist_out) {
    int t = blockIdx.x, b = blockIdx.y;
    int tid = threadIdx.x;
    const float4* f4 = (const float4*)(feat + ((size_t)b * TNUM + t) * DV);
    int j0 = tid * 4;
    float4 f = f4[tid];
    const double* m = mu   + (size_t)b * DV + j0;
    const double* r = rsig + (size_t)b * DV + j0;
    double c0 = (double)f.x - m[0];
    double c1 = (double)f.y - m[1];
    double c2 = (double)f.z - m[2];
    double c3 = (double)f.w - m[3];
    double acc = c0*c0*r[0] + c1*c1*r[1] + c2*c2*r[2] + c3*c3*r[3];
    acc = wave_reduce_sum(acc);
    __shared__ double sc[4];
    int wid = tid >> 6, lane = tid & 63;
    if (lane == 0) sc[wid] = acc;
    __syncthreads();
    if (tid == 0) {
        double d = sc[0] + sc[1] + sc[2] + sc[3];
        distw[(size_t)b * TNUM + t] = d;
        dist_out[b * TNUM + t] = (float)d;
    }
}

// ---------------- K5: median (radix-select) + top-18 + diversify ----------------
__global__ void __launch_bounds__(1024)
k_select(const double* __restrict__ distw,
         float* __restrict__ idx_out, int* __restrict__ idx_int) {
    int b = blockIdx.x;
    const double* w = distw + (size_t)b * TNUM;
    int tid = threadIdx.x;
    __shared__ unsigned int hist[256];
    __shared__ unsigned long long s_prefix;
    __shared__ int s_krem;
    __shared__ double s_med;
    __shared__ unsigned char removed[TNUM];
    __shared__ double red_v[16];
    __shared__ int red_i[16];
    __shared__ int s_cand[CANDN];

    if (tid == 0) { s_prefix = 0ULL; s_krem = (TNUM - 1) / 2; }
    for (int i = tid; i < TNUM; i += 1024) removed[i] = 0;
    __syncthreads();

    // 8-pass radix select for the lower median (rank 4095, 0-indexed)
    for (int p = 0; p < 8; ++p) {
        for (int c = tid; c < 256; c += 1024) hist[c] = 0;
        __syncthreads();
        unsigned long long pref = s_prefix;
        int dbits = 8 * p;
        for (int i = tid; i < TNUM; i += 1024) {
            unsigned long long u = enc_d(w[i]);
            bool ok = (dbits == 0) || ((u >> (64 - dbits)) == pref);
            if (ok) atomicAdd(&hist[(unsigned)((u >> (56 - dbits)) & 0xFFULL)], 1u);
        }
        __syncthreads();
        if (tid == 0) {
            int krem = s_krem;
            int c = 0;
            for (; c < 256; ++c) {
                int cnt = (int)hist[c];
                if (krem < cnt) break;
                krem -= cnt;
            }
            s_krem = krem;
            s_prefix = (s_prefix << 8) | (unsigned long long)c;
        }
        __syncthreads();
    }
    if (tid == 0) s_med = dec_d(s_prefix);
    __syncthreads();
    double med = s_med;

    // 18 iterations of stable argmin over (|d-med|, index) — matches lax.top_k order
    int lane = tid & 63, wid = tid >> 6;
    for (int it = 0; it < CANDN; ++it) {
        double bv = 1e300; int bi = TNUM;
        for (int i = tid; i < TNUM; i += 1024) {
            if (removed[i]) continue;
            double v = fabs(w[i] - med);
            if (v < bv || (v == bv && i < bi)) { bv = v; bi = i; }
        }
        for (int off = 32; off > 0; off >>= 1) {
            double ov = __shfl_down(bv, off);
            int    oi = __shfl_down(bi, off);
            if (ov < bv || (ov == bv && oi < bi)) { bv = ov; bi = oi; }
        }
        if (lane == 0) { red_v[wid] = bv; red_i[wid] = bi; }
        __syncthreads();
        if (tid == 0) {
            double cv = red_v[0]; int ci = red_i[0];
            for (int k = 1; k < 16; ++k)
                if (red_v[k] < cv || (red_v[k] == cv && red_i[k] < ci)) { cv = red_v[k]; ci = red_i[k]; }
            s_cand[it] = ci;
            removed[ci] = 1;
        }
        __syncthreads();
    }

    // greedy farthest-point diversify — serial, exact float32 semantics of reference
    if (tid == 0) {
        int cand[CANDN]; float candf[CANDN], mind[CANDN];
        for (int i = 0; i < CANDN; ++i) { cand[i] = s_cand[i]; candf[i] = (float)cand[i]; }
        for (int i = 0; i < CANDN; ++i) mind[i] = fabsf(candf[i] - candf[0]);
        const float NEG = -__builtin_huge_valf();
        mind[0] = NEG;
        int sel[KREP];
        sel[0] = cand[0];
        for (int s = 1; s < KREP; ++s) {
            int best = 0; float bm = mind[0];
            for (int i = 1; i < CANDN; ++i)
                if (mind[i] > bm) { bm = mind[i]; best = i; }   // strict > = first occurrence, matches argmax
            sel[s] = cand[best];
            for (int i = 0; i < CANDN; ++i)
                mind[i] = fminf(mind[i], fabsf(candf[i] - candf[best]));
            mind[best] = NEG;
        }
        for (int s = 0; s < KREP; ++s) {
            idx_out[b * KREP + s] = (float)sel[s];
            idx_int[b * KREP + s] = sel[s];
        }
    }
}

// ---------------- K6: qkv = rep @ in_w.T + in_b (gather fused) ----------------
__global__ void k_qkv(const float* __restrict__ feat, const int* __restrict__ idx_int,
                      const float* __restrict__ in_w, const float* __restrict__ in_b,
                      float* __restrict__ qkv) {
    int tok = blockIdx.x, o = blockIdx.y;   // token-fastest: 48 blocks share each weight row via L2
    int b = tok / KREP;
    int t = idx_int[tok];
    const float4* f4 = (const float4*)(feat + ((size_t)b * TNUM + t) * DV);
    const float4* w4 = (const float4*)(in_w + (size_t)o * DV);
    int tid = threadIdx.x;
    float4 f = f4[tid], w = w4[tid];
    float acc = f.x*w.x + f.y*w.y + f.z*w.z + f.w*w.w;
    acc = wave_reduce_sumf(acc);
    __shared__ float sc[4];
    int wid = tid >> 6, lane = tid & 63;
    if (lane == 0) sc[wid] = acc;
    __syncthreads();
    if (tid == 0)
        qkv[(size_t)tok * (3 * DV) + o] = sc[0] + sc[1] + sc[2] + sc[3] + in_b[o];
}

// ---------------- K7: per-(b,head) attention on 6 tokens ----------------
__global__ void k_attn(const float* __restrict__ qkv,
                       float* __restrict__ attn_h, float* __restrict__ ctx) {
    int h = blockIdx.x, b = blockIdx.y;
    __shared__ float sq[KREP * HD], sk[KREP * HD], sv[KREP * HD];
    __shared__ float sat[KREP * KREP];
    int tid = threadIdx.x;
    for (int p = tid; p < KREP * HD; p += 64) {
        int i = p >> 7, d = p & 127;
        size_t base = (size_t)(b * KREP + i) * (3 * DV) + h * HD + d;
        sq[p] = qkv[base];
        sk[p] = qkv[base + DV];
        sv[p] = qkv[base + 2 * DV];
    }
    __syncthreads();
    if (tid < KREP * KREP) {
        int i = tid / KREP, j = tid % KREP;
        float s = 0.0f;
        for (int d = 0; d < HD; ++d) s += sq[i * HD + d] * sk[j * HD + d];
        sat[tid] = s / sqrtf((float)HD);
    }
    __syncthreads();
    if (tid < KREP) {
        float m = sat[tid * KREP];
        for (int j = 1; j < KREP; ++j) m = fmaxf(m, sat[tid * KREP + j]);
        float sum = 0.0f;
        for (int j = 0; j < KREP; ++j) {
            float e = expf(sat[tid * KREP + j] - m);
            sum += e; sat[tid * KREP + j] = e;
        }
        float inv = 1.0f / sum;
        for (int j = 0; j < KREP; ++j) sat[tid * KREP + j] *= inv;
    }
    __syncthreads();
    if (tid < KREP * KREP)
        attn_h[(size_t)(b * NHEAD + h) * (KREP * KREP) + tid] = sat[tid];
    for (int p = tid; p < KREP * HD; p += 64) {
        int i = p >> 7, d = p & 127;
        float acc = 0.0f;
        for (int j = 0; j < KREP; ++j) acc += sat[i * KREP + j] * sv[j * HD + d];
        ctx[(size_t)(b * KREP + i) * DV + h * HD + d] = acc;
    }
}

// ---------------- K8: refined = ctx @ out_w.T + out_b ----------------
__global__ void k_proj(const float* __restrict__ ctx,
                       const float* __restrict__ out_w, const float* __restrict__ out_b,
                       float* __restrict__ refined) {
    int tok = blockIdx.x, o = blockIdx.y;
    const float4* f4 = (const float4*)(ctx + (size_t)tok * DV);
    const float4* w4 = (const float4*)(out_w + (size_t)o * DV);
    int tid = threadIdx.x;
    float4 f = f4[tid], w = w4[tid];
    float acc = f.x*w.x + f.y*w.y + f.z*w.z + f.w*w.w;
    acc = wave_reduce_sumf(acc);
    __shared__ float sc[4];
    int wid = tid >> 6, lane = tid & 63;
    if (lane == 0) sc[wid] = acc;
    __syncthreads();
    if (tid == 0)
        refined[(size_t)tok * DV + o] = sc[0] + sc[1] + sc[2] + sc[3] + out_b[o];
}

// ---------------- K9: attn mean over heads ----------------
__global__ void k_attnmean(const float* __restrict__ attn_h, float* __restrict__ out) {
    int e = threadIdx.x;
    if (e >= BNUM * KREP * KREP) return;
    int b = e / (KREP * KREP), r = e % (KREP * KREP);
    float s = 0.0f;
    for (int h = 0; h < NHEAD; ++h)
        s += attn_h[(size_t)(b * NHEAD + h) * (KREP * KREP) + r];
    out[e] = s * (1.0f / NHEAD);
}

// ---------------- launch ----------------
extern "C" void kernel_launch(void* const* d_in, const int* in_sizes, int n_in,
                              void* d_out, int out_size, void* d_ws, size_t ws_size,
                              hipStream_t stream) {
    const float* feat  = (const float*)d_in[0];
    const float* query = (const float*)d_in[1];
    const float* mu_w1 = (const float*)d_in[2];
    const float* mu_b1 = (const float*)d_in[3];
    const float* mu_g  = (const float*)d_in[4];
    const float* mu_bt = (const float*)d_in[5];
    const float* mu_w2 = (const float*)d_in[6];
    const float* mu_b2 = (const float*)d_in[7];
    const float* sg_w1 = (const float*)d_in[8];
    const float* sg_b1 = (const float*)d_in[9];
    const float* sg_g  = (const float*)d_in[10];
    const float* sg_bt = (const float*)d_in[11];
    const float* sg_w2 = (const float*)d_in[12];
    const float* sg_b2 = (const float*)d_in[13];
    const float* in_w  = (const float*)d_in[14];
    const float* in_b  = (const float*)d_in[15];
    const float* out_w = (const float*)d_in[16];
    const float* out_b = (const float*)d_in[17];

    float* out = (float*)d_out;
    // output layout: refined[8*6*1024], idx[48], dist[8*8192], mu[8192], sigma[8192], attn[288]
    float* out_refined = out;
    float* out_idx     = out + 49152;
    float* out_dist    = out + 49200;
    float* out_mu      = out + 114736;
    float* out_sg      = out + 122928;
    float* out_attn    = out + 131120;

    // workspace bump allocator (256B aligned)
    char* ws = (char*)d_ws;
    size_t off = 0;
    auto alloc = [&](size_t bytes) -> void* {
        void* p = (void*)(ws + off);
        off += (bytes + 255) & ~(size_t)255;
        return p;
    };
    double* h      = (double*)alloc((size_t)2 * BNUM * DV * sizeof(double));   // 128 KB
    double* muw    = (double*)alloc((size_t)BNUM * DV * sizeof(double));       //  64 KB
    double* rsig   = (double*)alloc((size_t)BNUM * DV * sizeof(double));       //  64 KB
    double* distw  = (double*)alloc((size_t)BNUM * TNUM * sizeof(double));     // 512 KB
    int*    idxi   = (int*)   alloc((size_t)BNUM * KREP * sizeof(int));
    float*  qkv    = (float*) alloc((size_t)BNUM * KREP * 3 * DV * sizeof(float)); // 576 KB
    float*  attn_h = (float*) alloc((size_t)BNUM * NHEAD * KREP * KREP * sizeof(float));
    float*  ctx    = (float*) alloc((size_t)BNUM * KREP * DV * sizeof(float));     // 192 KB

    k_mlp1<<<dim3(DV, BNUM, 2), 64, 0, stream>>>(query, mu_w1, mu_b1, sg_w1, sg_b1, h);
    k_ln  <<<dim3(BNUM, 2), 256, 0, stream>>>(h, mu_g, mu_bt, sg_g, sg_bt);
    k_mlp2<<<dim3(DV, BNUM, 2), 64, 0, stream>>>(h, mu_w2, mu_b2, sg_w2, sg_b2,
                                                 muw, rsig, out_mu, out_sg);
    k_dist<<<dim3(TNUM, BNUM), 256, 0, stream>>>(feat, muw, rsig, distw, out_dist);
    k_select<<<dim3(BNUM), 1024, 0, stream>>>(distw, out_idx, idxi);
    k_qkv <<<dim3(BNUM * KREP, 3 * DV), 256, 0, stream>>>(feat, idxi, in_w, in_b, qkv);
    k_attn<<<dim3(NHEAD, BNUM), 64, 0, stream>>>(qkv, attn_h, ctx);
    k_proj<<<dim3(BNUM * KREP, DV), 256, 0, stream>>>(ctx, out_w, out_b, out_refined);
    k_attnmean<<<dim3(1), 320, 0, stream>>>(attn_h, out_attn);
}